// Round 5
// baseline (77.708 us; speedup 1.0000x reference)
//
#include <hip/hip_runtime.h>
#include <math.h>

// ---- problem constants ----
#define B_N    2
#define S_LEN  2048
#define DMODEL 192
#define HQ_N   8
#define HKV_N  4
#define DH_N   24
#define KAUG   160   // 24 q/k + 64 cos + 64 sin + 8 zero pad (= 10 * 16)
#define LOG2E  1.44269504088896340736f

typedef __attribute__((ext_vector_type(8)))  short bf16x8;
typedef __attribute__((ext_vector_type(4)))  float f32x4;
typedef __attribute__((ext_vector_type(16))) float f32x16;

static __device__ __forceinline__ unsigned short f2bf(float f) {
    union { float f; unsigned u; } v; v.f = f;
    unsigned r = v.u + 0x7FFFu + ((v.u >> 16) & 1u);
    return (unsigned short)(r >> 16);
}
static __device__ __forceinline__ unsigned pk2(float a, float b) {
    return (unsigned)f2bf(a) | ((unsigned)f2bf(b) << 16);
}
static __device__ __forceinline__ unsigned cvtpk_bf16(float a, float b) {
    unsigned r;
    asm("v_cvt_pk_bf16_f32 %0, %1, %2" : "=v"(r) : "v"(a), "v"(b));
    return r;
}

typedef __attribute__((address_space(3))) unsigned short lds_us;
typedef const __attribute__((address_space(1))) unsigned short glb_us;
static __device__ __forceinline__ void gld16(const unsigned short* g, unsigned short* l) {
    __builtin_amdgcn_global_load_lds((glb_us*)g, (lds_us*)l, 16, 0, 0);
}

// ============================================================
// K0: phase kernel — sincos(x[:,128:]) -> QA/KA phase sections
// (Q side scaled by beta/64*log2e), zero pads, VT pad rows.
// Blocks [0,512): 8 rows each; [512,520): VT pad rows.
// ============================================================
__global__ __launch_bounds__(256) void phase_kernel(
    const float* __restrict__ x, const float* __restrict__ beta_p,
    unsigned short* __restrict__ QA, unsigned short* __restrict__ KA,
    unsigned short* __restrict__ VT)
{
    const int blk = blockIdx.x, tid = threadIdx.x;
    if (blk < 512) {
        const int r = tid >> 5, i = tid & 31;
        const int row = blk * 8 + r;
        const int b = row >> 11, s = row & (S_LEN - 1);
        const float bf = beta_p[0] * (1.0f / 64.0f) * LOG2E;
        float2 p = *(const float2*)&x[(size_t)row * DMODEL + 128 + 2 * i];
        float s0, c0, s1, c1;
        sincosf(p.x, &s0, &c0);
        sincosf(p.y, &s1, &c1);
        unsigned kc_ = pk2(c0, c1), ks_ = pk2(s0, s1);
        unsigned qc_ = pk2(c0 * bf, c1 * bf), qs_ = pk2(s0 * bf, s1 * bf);
        #pragma unroll
        for (int h = 0; h < 8; ++h) {
            unsigned short* base = QA + ((size_t)(b * 8 + h) * S_LEN + s) * KAUG;
            *(unsigned*)(base + 24 + 2 * i) = qc_;
            *(unsigned*)(base + 88 + 2 * i) = qs_;
        }
        #pragma unroll
        for (int kvh = 0; kvh < 4; ++kvh) {
            unsigned short* base = KA + ((size_t)(b * 4 + kvh) * S_LEN + s) * KAUG;
            *(unsigned*)(base + 24 + 2 * i) = kc_;
            *(unsigned*)(base + 88 + 2 * i) = ks_;
        }
        if (i < 12) {
            uint4 z = {0u, 0u, 0u, 0u};
            unsigned short* base = (i < 8)
                ? QA + ((size_t)(b * 8 + i) * S_LEN + s) * KAUG
                : KA + ((size_t)(b * 4 + (i - 8)) * S_LEN + s) * KAUG;
            *(uint4*)(base + 152) = z;
        }
    } else {
        const int j = blk - 512;
        unsigned short* base = VT + ((size_t)j * 32 + 24) * S_LEN;
        uint4 z = {0u, 0u, 0u, 0u};
        #pragma unroll
        for (int c = 0; c < 8; ++c)
            *(uint4*)(base + (size_t)(c * 256 + tid) * 8) = z;
    }
}

// ============================================================
// K1: QKV GEMM — reads x, Wq, Wkv as f32, converts to bf16 while
// staging into LDS.  Epilogue scatters q (alpha*SCALE*log2e), k, v.
// ============================================================
__global__ __launch_bounds__(256) void qkv_gemm_kernel(
    const float* __restrict__ x, const float* __restrict__ Wq,
    const float* __restrict__ Wkv, const float* __restrict__ alpha_p,
    unsigned short* __restrict__ QA, unsigned short* __restrict__ KA,
    unsigned short* __restrict__ VT)
{
    __shared__ __align__(16) unsigned short a_lds[64][200];
    __shared__ __align__(16) unsigned short b_lds[64][200];
    const int tid = threadIdx.x;
    const int wid = tid >> 6, lane = tid & 63, g = lane >> 4, lr = lane & 15;
    const int brow = blockIdx.x * 64;
    const int bcol = blockIdx.y * 64;

    #pragma unroll
    for (int c = 0; c < 12; ++c) {
        int idx = c * 256 + tid;           // 3072 float4s per matrix
        int r = idx / 48, ch = idx % 48;
        float4 v = *(const float4*)&x[(size_t)(brow + r) * 192 + ch * 4];
        uint2 w; w.x = pk2(v.x, v.y); w.y = pk2(v.z, v.w);
        *(uint2*)&a_lds[r][ch * 4] = w;
        int wr = bcol + r;
        const float* wsrc = (wr < 192) ? &Wq[(size_t)wr * 192 + ch * 4]
                                       : &Wkv[(size_t)(wr - 192) * 192 + ch * 4];
        float4 wv = *(const float4*)wsrc;
        uint2 w2; w2.x = pk2(wv.x, wv.y); w2.y = pk2(wv.z, wv.w);
        *(uint2*)&b_lds[r][ch * 4] = w2;
    }
    __syncthreads();

    f32x4 acc[4];
    #pragma unroll
    for (int nc = 0; nc < 4; ++nc) acc[nc] = (f32x4){0.f, 0.f, 0.f, 0.f};
    #pragma unroll
    for (int kc = 0; kc < 6; ++kc) {
        bf16x8 af = *(const bf16x8*)&a_lds[wid * 16 + lr][kc * 32 + g * 8];
        #pragma unroll
        for (int nc = 0; nc < 4; ++nc) {
            bf16x8 bfr = *(const bf16x8*)&b_lds[nc * 16 + lr][kc * 32 + g * 8];
            acc[nc] = __builtin_amdgcn_mfma_f32_16x16x32_bf16(af, bfr, acc[nc], 0, 0, 0);
        }
    }

    const float qs = alpha_p[0] * 0.20412414523193150818f * LOG2E;
    #pragma unroll
    for (int nc = 0; nc < 4; ++nc) {
        int c = bcol + nc * 16 + lr;
        #pragma unroll
        for (int r = 0; r < 4; ++r) {
            int row = brow + wid * 16 + g * 4 + r;
            int b = row >> 11, s = row & (S_LEN - 1);
            float v = acc[nc][r];
            if (c < 192) {
                int h = c / 24, d = c - 24 * h;
                QA[((size_t)(b * 8 + h) * S_LEN + s) * KAUG + d] = f2bf(v * qs);
            } else if (c < 288) {
                int cc = c - 192, kvh = cc / 24, d = cc - 24 * kvh;
                KA[((size_t)(b * 4 + kvh) * S_LEN + s) * KAUG + d] = f2bf(v);
            } else {
                int cc = c - 288, kvh = cc / 24, d = cc - 24 * kvh;
                VT[((size_t)(b * 4 + kvh) * 32 + d) * S_LEN + s] = f2bf(v);
            }
        }
    }
}

// ============================================================
// K2: fused flash attention — 32x32 MFMA, swapped operands.
// Block = 2 waves (128 thr), ONE 64-q tile; grid = 512 blocks.
// bid mapping: bid&7 = (b,kvh) -> XCD group (KA/VT L2 locality);
// i=bid>>3: i<32 -> h=2kvh,  t=31-i;  i>=32 -> h=2kvh+1, t=i-32
// (co-resident blocks i, i+32 have t + t' = 31 -> balanced CUs).
// KA/VT staged via global_load_lds (XOR-swizzled via pre-swizzled
// global source), double-buffered, counted vmcnt(12), raw s_barrier.
// Softmax in-register, log2 domain, defer-max (THR=8).
// P -> PV B-frags via cvt_pk + v_permlane32_swap_b32 (no LDS).
// ============================================================
__global__ __launch_bounds__(128) void attn_kernel(
    const unsigned short* __restrict__ QA, const unsigned short* __restrict__ KA,
    const unsigned short* __restrict__ VT, unsigned short* __restrict__ Ob)
{
    __shared__ __align__(16) unsigned short ka_lds[2][64 * KAUG]; // 2 x 20 KiB
    __shared__ __align__(16) unsigned short vt_lds[2][32 * 64];   // 2 x 4 KiB

    const int tid = threadIdx.x;
    const int wid = tid >> 6, lane = tid & 63;
    const int hi = lane >> 5, c31 = lane & 31;
    const int rs = c31 & 7, w2 = (c31 >> 1) & 3;

    const int bid = blockIdx.x;
    const int grp = bid & 7;                 // XCD group = (b,kvh)
    const int b = grp >> 2, kvh = grp & 3;
    const int i = bid >> 3;                  // 0..63 within group
    const int h = 2 * kvh + (i >> 5);
    const int ii = i & 31;
    const int t = (i < 32) ? (31 - ii) : ii;
    const int q = t * 64 + wid * 32 + c31;
    const int ntiles = t + 1;

    const unsigned short* ka_g = KA + (size_t)(b * 4 + kvh) * S_LEN * KAUG;
    const unsigned short* vt_g = VT + (size_t)(b * 4 + kvh) * 32 * S_LEN;

    // ---- Q fragments: 10 x b128 (dims 16kc + 8hi + 0..7), in regs ----
    bf16x8 qf[10];
    {
        const unsigned short* qa = QA + ((size_t)(b * 8 + h) * S_LEN + q) * KAUG + hi * 8;
        #pragma unroll
        for (int kc = 0; kc < 10; ++kc) qf[kc] = *(const bf16x8*)(qa + kc * 16);
    }

    // ---- staging addresses (tile-invariant): 10 KA + 2 VT gld16/thread ----
    int ka_soff[10], ka_doff[10], vt_soff[2], vt_doff[2];
    #pragma unroll
    for (int u = 0; u < 10; ++u) {
        int idx8 = wid * 640 + u * 64 + lane;        // granule index, [0,1280)
        int row = idx8 / 20, colg = idx8 % 20;
        int g2 = (colg < 16) ? (colg ^ (row & 7))
                             : (16 + ((colg & 3) ^ ((row >> 1) & 3)));
        ka_soff[u] = row * KAUG + g2 * 8;
        ka_doff[u] = idx8 * 8;
    }
    #pragma unroll
    for (int u = 0; u < 2; ++u) {
        int idx8 = wid * 128 + u * 64 + lane;        // [0,256)
        int row = idx8 >> 3, colg = idx8 & 7;
        vt_soff[u] = row * S_LEN + (colg ^ (row & 7)) * 8;
        vt_doff[u] = idx8 * 8;
    }

    // ---- ds_read offsets (shorts), tile-invariant ----
    unsigned offA[10], offV[4];
    #pragma unroll
    for (int kc = 0; kc < 10; ++kc) {
        int g = 2 * kc + hi;
        int pg = (kc < 8) ? (g ^ rs) : (16 + ((g & 3) ^ w2));
        offA[kc] = c31 * KAUG + pg * 8;
    }
    #pragma unroll
    for (int ks = 0; ks < 4; ++ks)
        offV[ks] = c31 * 64 + ((2 * ks + hi) ^ rs) * 8;

    auto STAGE = [&](int bufsel, int kt_) {
        const int n0 = kt_ * 64;
        const unsigned short* kg = ka_g + (size_t)n0 * KAUG;
        #pragma unroll
        for (int u = 0; u < 10; ++u)
            gld16(kg + ka_soff[u], &ka_lds[bufsel][ka_doff[u]]);
        #pragma unroll
        for (int u = 0; u < 2; ++u)
            gld16(vt_g + n0 + vt_soff[u], &vt_lds[bufsel][vt_doff[u]]);
    };

    f32x16 acc = {0,0,0,0,0,0,0,0,0,0,0,0,0,0,0,0};
    float m = -1e30f, l = 0.f;

    STAGE(0, 0);
    if (ntiles > 1) STAGE(1, 1);

    for (int kt = 0; kt < ntiles; ++kt) {
        const int buf = kt & 1;
        if (kt + 1 < ntiles) asm volatile("s_waitcnt vmcnt(12)" ::: "memory");
        else                 asm volatile("s_waitcnt vmcnt(0)" ::: "memory");
        __builtin_amdgcn_s_barrier();

        const unsigned short* kb = &ka_lds[buf][0];
        const unsigned short* vb = &vt_lds[buf][0];
        f32x16 s0 = {0,0,0,0,0,0,0,0,0,0,0,0,0,0,0,0};
        f32x16 s1 = {0,0,0,0,0,0,0,0,0,0,0,0,0,0,0,0};
        #pragma unroll
        for (int kc = 0; kc < 10; ++kc) {
            bf16x8 a0 = *(const bf16x8*)(kb + offA[kc]);
            bf16x8 a1 = *(const bf16x8*)(kb + offA[kc] + 32 * KAUG);
            s0 = __builtin_amdgcn_mfma_f32_32x32x16_bf16(a0, qf[kc], s0, 0, 0, 0);
            s1 = __builtin_amdgcn_mfma_f32_32x32x16_bf16(a1, qf[kc], s1, 0, 0, 0);
        }
        // causal mask on the diagonal tile
        if (kt == ntiles - 1) {
            const int qc = wid * 32 + c31;
            #pragma unroll
            for (int r = 0; r < 16; ++r) {
                int krow = (r & 3) + 8 * (r >> 2) + 4 * hi;
                if (krow > qc)      s0[r] = -1e30f;
                if (krow + 32 > qc) s1[r] = -1e30f;
            }
        }
        // ---- online softmax with defer-max ----
        float tmax = s0[0];
        #pragma unroll
        for (int r = 1; r < 16; ++r) tmax = fmaxf(tmax, s0[r]);
        #pragma unroll
        for (int r = 0; r < 16; ++r) tmax = fmaxf(tmax, s1[r]);
        tmax = fmaxf(tmax, __shfl_xor(tmax, 32, 64));
        if (!__all(tmax <= m + 8.f)) {
            float mnew = fmaxf(m, tmax);
            float corr = __builtin_amdgcn_exp2f(m - mnew);
            m = mnew;
            l *= corr;
            #pragma unroll
            for (int r = 0; r < 16; ++r) acc[r] *= corr;
        }
        float ts = 0.f;
        #pragma unroll
        for (int r = 0; r < 16; ++r) {
            s0[r] = __builtin_amdgcn_exp2f(s0[r] - m);
            s1[r] = __builtin_amdgcn_exp2f(s1[r] - m);
            ts += s0[r] + s1[r];
        }
        ts += __shfl_xor(ts, 32, 64);
        l += ts;

        // ---- pack P (bf16 pairs) ----
        unsigned W0[8], W1[8];
        #pragma unroll
        for (int j = 0; j < 8; ++j) {
            W0[j] = cvtpk_bf16(s0[2 * j], s0[2 * j + 1]);
            W1[j] = cvtpk_bf16(s1[2 * j], s1[2 * j + 1]);
        }
        // ---- PV: B-frag via permlane32_swap, A = V^T from LDS ----
        union U16 { unsigned d[4]; bf16x8 v; };
#define PVSTEP(Warr, e, ks) { \
        unsigned x_  = Warr[4 * e],     y_  = Warr[4 * e + 2]; \
        unsigned x2_ = Warr[4 * e + 1], y2_ = Warr[4 * e + 3]; \
        asm volatile("v_permlane32_swap_b32 %0, %1" : "+v"(x_),  "+v"(y_)); \
        asm volatile("v_permlane32_swap_b32 %0, %1" : "+v"(x2_), "+v"(y2_)); \
        U16 pf; pf.d[0] = x_; pf.d[1] = x2_; pf.d[2] = y_; pf.d[3] = y2_; \
        bf16x8 av = *(const bf16x8*)(vb + offV[ks]); \
        acc = __builtin_amdgcn_mfma_f32_32x32x16_bf16(av, pf.v, acc, 0, 0, 0); }
        PVSTEP(W0, 0, 0)
        PVSTEP(W0, 1, 1)
        PVSTEP(W1, 0, 2)
        PVSTEP(W1, 1, 3)
#undef PVSTEP

        __builtin_amdgcn_s_barrier();
        if (kt + 2 < ntiles) STAGE(buf, kt + 2);
    }

    // ---- finalize: O[b][q][h*24+d], d = (reg&3)+8*(reg>>2)+4*hi ----
    const float invl = 1.0f / l;
    unsigned short* ob = Ob + ((size_t)b * S_LEN + q) * DMODEL + h * 24 + 4 * hi;
    #pragma unroll
    for (int k = 0; k < 3; ++k) {
        unsigned u0 = pk2(acc[4 * k] * invl,     acc[4 * k + 1] * invl);
        unsigned u1 = pk2(acc[4 * k + 2] * invl, acc[4 * k + 3] * invl);
        *(unsigned*)(ob + 8 * k)     = u0;
        *(unsigned*)(ob + 8 * k + 2) = u1;
    }
}

// ============================================================
// K3: out = Ob @ Wo^T  (A bf16; B converted f32->bf16 in staging)
// ============================================================
__global__ __launch_bounds__(256) void proj_gemm_kernel(
    const unsigned short* __restrict__ Ob, const float* __restrict__ Wo,
    float* __restrict__ out)
{
    __shared__ __align__(16) unsigned short a_lds[64][200];
    __shared__ __align__(16) unsigned short b_lds[64][200];
    const int tid = threadIdx.x;
    const int wid = tid >> 6, lane = tid & 63, g = lane >> 4, lr = lane & 15;
    const int brow = blockIdx.x * 64;
    const int bcol = blockIdx.y * 64;

    #pragma unroll
    for (int c = 0; c < 6; ++c) {
        int idx = c * 256 + tid;
        int r = idx / 24, ch = idx % 24;
        *(uint4*)&a_lds[r][ch * 8] = *(const uint4*)&Ob[(size_t)(brow + r) * 192 + ch * 8];
    }
    #pragma unroll
    for (int c = 0; c < 12; ++c) {
        int idx = c * 256 + tid;
        int r = idx / 48, ch = idx % 48;
        float4 wv = *(const float4*)&Wo[(size_t)(bcol + r) * 192 + ch * 4];
        uint2 w2; w2.x = pk2(wv.x, wv.y); w2.y = pk2(wv.z, wv.w);
        *(uint2*)&b_lds[r][ch * 4] = w2;
    }
    __syncthreads();

    f32x4 acc[4];
    #pragma unroll
    for (int nc = 0; nc < 4; ++nc) acc[nc] = (f32x4){0.f, 0.f, 0.f, 0.f};
    #pragma unroll
    for (int kc = 0; kc < 6; ++kc) {
        bf16x8 af = *(const bf16x8*)&a_lds[wid * 16 + lr][kc * 32 + g * 8];
        #pragma unroll
        for (int nc = 0; nc < 4; ++nc) {
            bf16x8 bfr = *(const bf16x8*)&b_lds[nc * 16 + lr][kc * 32 + g * 8];
            acc[nc] = __builtin_amdgcn_mfma_f32_16x16x32_bf16(af, bfr, acc[nc], 0, 0, 0);
        }
    }

    #pragma unroll
    for (int nc = 0; nc < 4; ++nc) {
        int c = bcol + nc * 16 + lr;
        #pragma unroll
        for (int r = 0; r < 4; ++r) {
            int row = brow + wid * 16 + g * 4 + r;
            out[(size_t)row * 192 + c] = acc[nc][r];
        }
    }
}

// ============================================================
extern "C" void kernel_launch(void* const* d_in, const int* in_sizes, int n_in,
                              void* d_out, int out_size, void* d_ws, size_t ws_size,
                              hipStream_t stream) {
    const float* x     = (const float*)d_in[0];
    const float* Wq    = (const float*)d_in[1];
    const float* Wkv   = (const float*)d_in[2];
    const float* Wo    = (const float*)d_in[3];
    const float* alpha = (const float*)d_in[4];
    const float* beta  = (const float*)d_in[5];

    char* ws = (char*)d_ws;
    const size_t QA_BYTES = (size_t)B_N * 8 * S_LEN * KAUG * 2;   // 10,485,760
    const size_t KA_BYTES = (size_t)B_N * 4 * S_LEN * KAUG * 2;   //  5,242,880
    const size_t VT_BYTES = (size_t)B_N * 4 * 32 * S_LEN * 2;     //  1,048,576
    unsigned short* QA = (unsigned short*)ws;
    unsigned short* KA = (unsigned short*)(ws + QA_BYTES);
    unsigned short* VT = (unsigned short*)(ws + QA_BYTES + KA_BYTES);
    unsigned short* Ob = (unsigned short*)(ws + QA_BYTES + KA_BYTES + VT_BYTES);
    float* out = (float*)d_out;

    hipLaunchKernelGGL(phase_kernel, dim3(520), dim3(256), 0, stream,
                       x, beta, QA, KA, VT);
    hipLaunchKernelGGL(qkv_gemm_kernel, dim3(64, 6), dim3(256), 0, stream,
                       x, Wq, Wkv, alpha, QA, KA, VT);
    hipLaunchKernelGGL(attn_kernel, dim3(512), dim3(128), 0, stream,
                       QA, KA, VT, Ob);
    hipLaunchKernelGGL(proj_gemm_kernel, dim3(64, 3), dim3(256), 0, stream,
                       Ob, Wo, out);
}